// Round 3
// baseline (335.837 us; speedup 1.0000x reference)
//
#include <hip/hip_runtime.h>
#include <math.h>

#define Bp 32
#define Vp 48
#define Ip 24
#define Hp 768
#define EPS 1e-5f

#define EFFECTS_SIZE (Bp*Ip*Vp*Hp)   // 28,311,552
#define GRAPH_SIZE   (Bp*Vp*Vp)      // 73,728
#define ENC_SIZE     (Bp*Vp*Hp)      // 1,179,648
#define MS           (Hp*Hp)         // packed matrix size in ushorts

typedef __attribute__((ext_vector_type(8))) short short8;
typedef __attribute__((ext_vector_type(4))) float floatx4;
typedef __attribute__((ext_vector_type(4))) unsigned int uintx4;

__device__ __forceinline__ unsigned short f2bf(float f) {
    unsigned int u = __float_as_uint(f);
    u += 0x7fffu + ((u >> 16) & 1u);
    return (unsigned short)(u >> 16);
}
__device__ __forceinline__ unsigned int f2bf2(float a, float b) {
    return (unsigned int)f2bf(a) | ((unsigned int)f2bf(b) << 16);
}

// ---------------------------------------------------------------------------
// Pack 6 H x H weight blocks into MFMA B-operand layout (bf16).
// packed[m][((T*24+kb)*64+lane)*8 + j] = W[kb*32+(lane>>4)*8+j][T*16+(lane&15)]
// slots: 0=W_enc 1=Wg1a 2=Wg1b 3=Wi1b 4=Wi1a 5=Wi2
// ---------------------------------------------------------------------------
__global__ __launch_bounds__(256) void pack_weights(
    const float* __restrict__ W_enc, const float* __restrict__ Wg1,
    const float* __restrict__ Wi1, const float* __restrict__ Wi2,
    unsigned short* __restrict__ packed)
{
    const int bid = blockIdx.x;          // 0..1727
    const int m = bid / 288;
    const int rem = bid - m * 288;
    const int T = rem / 6;
    const int u = rem - T * 6;
    const float* src;
    switch (m) {
        case 0: src = W_enc; break;
        case 1: src = Wg1; break;
        case 2: src = Wg1 + Hp * Hp; break;
        case 3: src = Wi1 + Hp * Hp; break;
        case 4: src = Wi1; break;
        default: src = Wi2; break;
    }
    unsigned short* dst = packed + (size_t)m * MS;
    const int lane = threadIdx.x & 63;
    const int kq = threadIdx.x >> 6;     // 0..3
    const int col = T * 16 + (lane & 15);
    const int krow0 = (lane >> 4) * 8;
    const int kb = kq + 4 * u;           // 0..23
    unsigned int w[4];
#pragma unroll
    for (int p2 = 0; p2 < 4; ++p2) {
        float f0 = src[(size_t)(kb * 32 + krow0 + 2 * p2)     * Hp + col];
        float f1 = src[(size_t)(kb * 32 + krow0 + 2 * p2 + 1) * Hp + col];
        w[p2] = f2bf2(f0, f1);
    }
    uintx4 v; v.x = w[0]; v.y = w[1]; v.z = w[2]; v.w = w[3];
    *(uintx4*)(dst + ((size_t)(T * 24 + kb) * 64 + lane) * 8) = v;
}

// ---------------------------------------------------------------------------
// Convert variables+interventions fp32 -> bf16; block 0 also builds bias2304.
// ---------------------------------------------------------------------------
__global__ __launch_bounds__(256) void convert_inputs(
    const float* __restrict__ vars, const float* __restrict__ intv,
    const float* __restrict__ bg1, const float* __restrict__ bi1,
    unsigned short* __restrict__ varb, unsigned short* __restrict__ intvb,
    float* __restrict__ bias2304)
{
    const int p = blockIdx.x * 256 + threadIdx.x;
    const int VPn = ENC_SIZE / 2;
    if (p < VPn) {
        float2 f = ((const float2*)vars)[p];
        ((unsigned int*)varb)[p] = f2bf2(f.x, f.y);
    } else {
        int q = p - VPn;
        float2 f = ((const float2*)intv)[q];
        ((unsigned int*)intvb)[q] = f2bf2(f.x, f.y);
    }
    if (blockIdx.x == 0) {
        for (int t = threadIdx.x; t < 2304; t += 256)
            bias2304[t] = (t < 768) ? 0.0f : (t < 1536 ? bg1[t - 768] : bi1[t - 1536]);
    }
}

// ---------------------------------------------------------------------------
// gemm48: C[M x N] = A_bf16[M x 768] @ Bpacked (+bias). Block = 48 rows x 768
// cols. A staged in swizzled MFMA-fragment LDS layout (72 KB). Per wave:
// 12 T-groups in 2 passes of 6, acc[3][6], B 2-deep reg prefetch, A dbuf.
// ---------------------------------------------------------------------------
__global__ __launch_bounds__(256) void gemm48(
    const unsigned short* __restrict__ A, const unsigned short* __restrict__ Bpk,
    const float* __restrict__ bias, float* __restrict__ C, int ldc)
{
    __shared__ unsigned short Asl[3 * 24 * 64 * 8];   // 73,728 B
    const int tid = threadIdx.x, wave = tid >> 6, lane = tid & 63;
    const int m0 = blockIdx.x * 48;

    // stage A into swizzled fragment layout: unit = (mt*24+kb)*64 + (L^(kb&7))
#pragma unroll
    for (int uu = 0; uu < 18; ++uu) {
        const int s = tid + 256 * uu;                 // 0..4607
        const int mt = s / 1536;
        const int r2 = s - mt * 1536;
        const int kb = r2 >> 6;
        const int L  = r2 & 63;
        const int mrow = L & 15, kq = L >> 4;
        uintx4 v = *(const uintx4*)(A + (size_t)(m0 + mt * 16 + mrow) * Hp + kb * 32 + kq * 8);
        const int phys = (mt * 24 + kb) * 64 + (L ^ (kb & 7));
        *(uintx4*)(&Asl[phys * 8]) = v;
    }
    __syncthreads();

    const int mrow = lane & 15, kq = lane >> 4;
    const floatx4 z = {0.f, 0.f, 0.f, 0.f};

#pragma unroll
    for (int G = 0; G < 2; ++G) {
        const int Tg0 = blockIdx.y * 48 + wave * 12 + G * 6;
        const unsigned short* Bbase = Bpk + (size_t)Tg0 * 12288 + lane * 8;
        floatx4 acc[3][6];
#pragma unroll
        for (int mt = 0; mt < 3; ++mt)
#pragma unroll
            for (int nt = 0; nt < 6; ++nt) acc[mt][nt] = z;

        short8 bbuf[3][6], abuf[2][3];
#pragma unroll
        for (int nt = 0; nt < 6; ++nt) {
            bbuf[0][nt] = *(const short8*)(Bbase + (size_t)nt * 12288);
            bbuf[1][nt] = *(const short8*)(Bbase + (size_t)nt * 12288 + 512);
        }
#pragma unroll
        for (int mt = 0; mt < 3; ++mt)
            abuf[0][mt] = *(const short8*)(&Asl[((mt * 24) * 64 + lane) * 8]);

#pragma unroll
        for (int kb = 0; kb < 24; ++kb) {
            if (kb + 2 < 24) {
#pragma unroll
                for (int nt = 0; nt < 6; ++nt)
                    bbuf[(kb + 2) % 3][nt] =
                        *(const short8*)(Bbase + (size_t)nt * 12288 + (kb + 2) * 512);
            }
            if (kb + 1 < 24) {
#pragma unroll
                for (int mt = 0; mt < 3; ++mt)
                    abuf[(kb + 1) & 1][mt] = *(const short8*)(
                        &Asl[((mt * 24 + kb + 1) * 64 + (lane ^ ((kb + 1) & 7))) * 8]);
            }
#pragma unroll
            for (int mt = 0; mt < 3; ++mt)
#pragma unroll
                for (int nt = 0; nt < 6; ++nt)
                    acc[mt][nt] = __builtin_amdgcn_mfma_f32_16x16x32_bf16(
                        abuf[kb & 1][mt], bbuf[kb % 3][nt], acc[mt][nt], 0, 0, 0);
        }

#pragma unroll
        for (int nt = 0; nt < 6; ++nt) {
            const int colg = (Tg0 + nt) * 16 + mrow;
            const float bv = bias ? bias[colg] : 0.0f;
#pragma unroll
            for (int mt = 0; mt < 3; ++mt)
#pragma unroll
                for (int r = 0; r < 4; ++r)
                    C[(size_t)(m0 + mt * 16 + kq * 4 + r) * ldc + colg] = acc[mt][nt][r] + bv;
        }
    }
}

// ---------------------------------------------------------------------------
// LN+ReLU -> enc fp32 (output) and enc bf16 (next GEMM A)
// ---------------------------------------------------------------------------
__global__ __launch_bounds__(256) void ln_relu(
    const float* __restrict__ pre, const float* __restrict__ g,
    const float* __restrict__ be, float* __restrict__ encf,
    unsigned short* __restrict__ encb)
{
    const int wave = threadIdx.x >> 6, lane = threadIdx.x & 63;
    const int row = blockIdx.x * 4 + wave;
    const float2* rp = (const float2*)(pre + (size_t)row * Hp);
    float2 x[6]; float s = 0.f, q = 0.f;
#pragma unroll
    for (int c = 0; c < 6; ++c) {
        x[c] = rp[lane + 64 * c];
        s += x[c].x + x[c].y;
        q += x[c].x * x[c].x + x[c].y * x[c].y;
    }
#pragma unroll
    for (int m = 1; m < 64; m <<= 1) { s += __shfl_xor(s, m, 64); q += __shfl_xor(q, m, 64); }
    const float mu = s * (1.0f / Hp);
    const float var = q * (1.0f / Hp) - mu * mu;
    const float rs = rsqrtf(var + EPS);
    float2* of = (float2*)(encf + (size_t)row * Hp);
    unsigned int* ob = (unsigned int*)(encb + (size_t)row * Hp);
#pragma unroll
    for (int c = 0; c < 6; ++c) {
        const float2 g2 = ((const float2*)g)[lane + 64 * c];
        const float2 b2 = ((const float2*)be)[lane + 64 * c];
        float y0 = fmaxf((x[c].x - mu) * rs * g2.x + b2.x, 0.f);
        float y1 = fmaxf((x[c].y - mu) * rs * g2.y + b2.y, 0.f);
        of[lane + 64 * c] = make_float2(y0, y1);
        ob[lane + 64 * c] = f2bf2(y0, y1);
    }
}

// ---------------------------------------------------------------------------
// Causal graph: block = (b,i); each wave handles 12 j's.
// ---------------------------------------------------------------------------
__global__ __launch_bounds__(256) void graph_kernel(
    const float* __restrict__ ws2, const float* __restrict__ gg_,
    const float* __restrict__ bb_, const float* __restrict__ Wg2,
    const float* __restrict__ bg2, float* __restrict__ out)
{
    const int wave = threadIdx.x >> 6, lane = threadIdx.x & 63;
    const int p = blockIdx.x;
    const int b = p / Vp, i = p - b * Vp;
    const float* hi_row = ws2 + (size_t)p * 2304;
    float ri[12], gg[12], bb[12], w2[12];
#pragma unroll
    for (int c = 0; c < 12; ++c) {
        const int k = lane + 64 * c;
        ri[c] = hi_row[k]; gg[c] = gg_[k]; bb[c] = bb_[k]; w2[c] = Wg2[k];
    }
    const float bg2v = bg2[0];
    const int j0 = wave * 12;
    for (int jj = 0; jj < 12; ++jj) {
        const int j = j0 + jj;
        const float* hj_row = ws2 + (size_t)(b * Vp + j) * 2304 + 768;
        float x[12], s = 0.f, q = 0.f;
#pragma unroll
        for (int c = 0; c < 12; ++c) {
            x[c] = ri[c] + hj_row[lane + 64 * c];
            s += x[c]; q += x[c] * x[c];
        }
#pragma unroll
        for (int m = 1; m < 64; m <<= 1) { s += __shfl_xor(s, m, 64); q += __shfl_xor(q, m, 64); }
        const float mu = s * (1.0f / Hp);
        const float var = q * (1.0f / Hp) - mu * mu;
        const float rs = rsqrtf(var + EPS);
        float pd = 0.f;
#pragma unroll
        for (int c = 0; c < 12; ++c) {
            float y = fmaxf((x[c] - mu) * rs * gg[c] + bb[c], 0.f);
            pd = fmaf(y, w2[c], pd);
        }
#pragma unroll
        for (int m = 1; m < 64; m <<= 1) pd += __shfl_xor(pd, m, 64);
        if (lane == 0) {
            float sc = (i == j) ? 0.0f : 1.0f / (1.0f + expf(-(pd + bg2v)));
            out[(size_t)p * Vp + j] = sc;
        }
    }
}

// ---------------------------------------------------------------------------
// effects48: block = one (b,i) pair x all 48 j's (48 rows).
// Phase 1: LN+ReLU -> bf16 swizzled-fragment LDS (half-wave per row).
// Phase 2: identical pipelined MFMA structure as gemm48.
// ---------------------------------------------------------------------------
__global__ __launch_bounds__(256) void effects48(
    const float* __restrict__ ha, const float* __restrict__ ws2,
    const float* __restrict__ g_i, const float* __restrict__ b_i,
    const unsigned short* __restrict__ Bpk, const float* __restrict__ bi2,
    float* __restrict__ out)
{
    __shared__ unsigned short Asl[3 * 24 * 64 * 8];   // 73,728 B
    const int tid = threadIdx.x, wave = tid >> 6, lane = tid & 63;
    const int bi = blockIdx.x;           // 0..767 = b*Ip + i
    const int b = bi / Ip;
    const int half = lane >> 5, hl = lane & 31;

    // per-lane chunk float4 indices: {2hl+64t, 2hl+1+64t}, t=0..2
    const floatx4* hap = (const floatx4*)(ha + (size_t)bi * Hp);
    const floatx4* gp = (const floatx4*)g_i;
    const floatx4* bp = (const floatx4*)b_i;
    floatx4 hav[6], gv[6], bv[6];
#pragma unroll
    for (int t = 0; t < 3; ++t) {
        hav[2*t]   = hap[2*hl + 64*t];     hav[2*t+1] = hap[2*hl + 1 + 64*t];
        gv[2*t]    = gp[2*hl + 64*t];      gv[2*t+1]  = gp[2*hl + 1 + 64*t];
        bv[2*t]    = bp[2*hl + 64*t];      bv[2*t+1]  = bp[2*hl + 1 + 64*t];
    }

#pragma unroll
    for (int p = 0; p < 6; ++p) {
        const int u = wave * 12 + 2 * p + half;       // local row = j, 0..47
        const floatx4* hbp = (const floatx4*)(ws2 + (size_t)(b * Vp + u) * 2304 + 1536);
        floatx4 x[6]; float s = 0.f, q = 0.f;
#pragma unroll
        for (int t = 0; t < 3; ++t) {
            x[2*t]   = hav[2*t]   + hbp[2*hl + 64*t];
            x[2*t+1] = hav[2*t+1] + hbp[2*hl + 1 + 64*t];
        }
#pragma unroll
        for (int c = 0; c < 6; ++c) {
            s += x[c].x + x[c].y + x[c].z + x[c].w;
            q += x[c].x*x[c].x + x[c].y*x[c].y + x[c].z*x[c].z + x[c].w*x[c].w;
        }
#pragma unroll
        for (int m = 1; m < 32; m <<= 1) { s += __shfl_xor(s, m, 64); q += __shfl_xor(q, m, 64); }
        const float mu = s * (1.0f / Hp);
        const float var = q * (1.0f / Hp) - mu * mu;
        const float rs = rsqrtf(var + EPS);
        const int mt = u >> 4, mrow = u & 15;
#pragma unroll
        for (int t = 0; t < 3; ++t) {
            float y0 = fmaxf((x[2*t].x   - mu) * rs * gv[2*t].x   + bv[2*t].x,   0.f);
            float y1 = fmaxf((x[2*t].y   - mu) * rs * gv[2*t].y   + bv[2*t].y,   0.f);
            float y2 = fmaxf((x[2*t].z   - mu) * rs * gv[2*t].z   + bv[2*t].z,   0.f);
            float y3 = fmaxf((x[2*t].w   - mu) * rs * gv[2*t].w   + bv[2*t].w,   0.f);
            float y4 = fmaxf((x[2*t+1].x - mu) * rs * gv[2*t+1].x + bv[2*t+1].x, 0.f);
            float y5 = fmaxf((x[2*t+1].y - mu) * rs * gv[2*t+1].y + bv[2*t+1].y, 0.f);
            float y6 = fmaxf((x[2*t+1].z - mu) * rs * gv[2*t+1].z + bv[2*t+1].z, 0.f);
            float y7 = fmaxf((x[2*t+1].w - mu) * rs * gv[2*t+1].w + bv[2*t+1].w, 0.f);
            const int cpk = hl + 32 * t;              // chunk 0..95
            const int kb = cpk >> 2, kq2 = cpk & 3;
            const int phys = (mt * 24 + kb) * 64 + ((kq2 * 16 + mrow) ^ (kb & 7));
            uintx4 v;
            v.x = f2bf2(y0, y1); v.y = f2bf2(y2, y3);
            v.z = f2bf2(y4, y5); v.w = f2bf2(y6, y7);
            *(uintx4*)(&Asl[phys * 8]) = v;
        }
    }
    __syncthreads();

    // ---- Phase 2: pipelined MFMA vs packed Wi2 ----
    const int mrow = lane & 15, kq = lane >> 4;
    const floatx4 z = {0.f, 0.f, 0.f, 0.f};
#pragma unroll
    for (int G = 0; G < 2; ++G) {
        const int Tg0 = wave * 12 + G * 6;
        const unsigned short* Bbase = Bpk + (size_t)Tg0 * 12288 + lane * 8;
        floatx4 acc[3][6];
#pragma unroll
        for (int mt = 0; mt < 3; ++mt)
#pragma unroll
            for (int nt = 0; nt < 6; ++nt) acc[mt][nt] = z;

        short8 bbuf[3][6], abuf[2][3];
#pragma unroll
        for (int nt = 0; nt < 6; ++nt) {
            bbuf[0][nt] = *(const short8*)(Bbase + (size_t)nt * 12288);
            bbuf[1][nt] = *(const short8*)(Bbase + (size_t)nt * 12288 + 512);
        }
#pragma unroll
        for (int mt = 0; mt < 3; ++mt)
            abuf[0][mt] = *(const short8*)(&Asl[((mt * 24) * 64 + lane) * 8]);

#pragma unroll
        for (int kb = 0; kb < 24; ++kb) {
            if (kb + 2 < 24) {
#pragma unroll
                for (int nt = 0; nt < 6; ++nt)
                    bbuf[(kb + 2) % 3][nt] =
                        *(const short8*)(Bbase + (size_t)nt * 12288 + (kb + 2) * 512);
            }
            if (kb + 1 < 24) {
#pragma unroll
                for (int mt = 0; mt < 3; ++mt)
                    abuf[(kb + 1) & 1][mt] = *(const short8*)(
                        &Asl[((mt * 24 + kb + 1) * 64 + (lane ^ ((kb + 1) & 7))) * 8]);
            }
#pragma unroll
            for (int mt = 0; mt < 3; ++mt)
#pragma unroll
                for (int nt = 0; nt < 6; ++nt)
                    acc[mt][nt] = __builtin_amdgcn_mfma_f32_16x16x32_bf16(
                        abuf[kb & 1][mt], bbuf[kb % 3][nt], acc[mt][nt], 0, 0, 0);
        }

#pragma unroll
        for (int nt = 0; nt < 6; ++nt) {
            const int colg = (Tg0 + nt) * 16 + mrow;
            const float biasv = bi2[colg];
#pragma unroll
            for (int mt = 0; mt < 3; ++mt) {
#pragma unroll
                for (int r = 0; r < 4; ++r) {
                    out[(size_t)(bi * 48 + mt * 16 + kq * 4 + r) * Hp + colg] =
                        acc[mt][nt][r] + biasv;
                }
            }
        }
    }
}

// ---------------------------------------------------------------------------
extern "C" void kernel_launch(void* const* d_in, const int* in_sizes, int n_in,
                              void* d_out, int out_size, void* d_ws, size_t ws_size,
                              hipStream_t stream) {
    const float* variables     = (const float*)d_in[0];
    const float* interventions = (const float*)d_in[1];
    const float* W_enc  = (const float*)d_in[2];
    const float* b_enc  = (const float*)d_in[3];
    const float* g_enc  = (const float*)d_in[4];
    const float* be_enc = (const float*)d_in[5];
    const float* Wg1 = (const float*)d_in[6];
    const float* bg1 = (const float*)d_in[7];
    const float* g_g = (const float*)d_in[8];
    const float* b_g = (const float*)d_in[9];
    const float* Wg2 = (const float*)d_in[10];
    const float* bg2 = (const float*)d_in[11];
    const float* Wi1 = (const float*)d_in[12];
    const float* bi1 = (const float*)d_in[13];
    const float* g_i = (const float*)d_in[14];
    const float* b_i = (const float*)d_in[15];
    const float* Wi2 = (const float*)d_in[16];
    const float* bi2 = (const float*)d_in[17];

    float* out = (float*)d_out;
    float* effects = out;
    float* graph = out + EFFECTS_SIZE;
    float* enc_f = out + EFFECTS_SIZE + GRAPH_SIZE;

    char* wsb = (char*)d_ws;
    unsigned short* packedW = (unsigned short*)wsb;                   // 7,077,888 B
    float* ws2  = (float*)(wsb + 7077888);                            // [1536][2304] fp32
    float* pre1 = ws2;                                                // alias (consumed first)
    float* ha   = (float*)(wsb + 7077888 + 14155776);                 // [768][768] fp32
    unsigned short* varb  = (unsigned short*)(wsb + 23592960);
    unsigned short* intvb = (unsigned short*)(wsb + 25952256);
    unsigned short* encb  = (unsigned short*)(wsb + 27131904);
    float* bias2304 = (float*)(wsb + 29491200);

    pack_weights<<<1728, 256, 0, stream>>>(W_enc, Wg1, Wi1, Wi2, packedW);
    convert_inputs<<<3456, 256, 0, stream>>>(variables, interventions, bg1, bi1,
                                             varb, intvb, bias2304);
    // pre1 = var @ W_enc + b_enc        [1536 x 768]
    gemm48<<<dim3(32, 1), 256, 0, stream>>>(varb, packedW, b_enc, pre1, Hp);
    // enc (fp32 to d_out, bf16 to ws)
    ln_relu<<<384, 256, 0, stream>>>(pre1, g_enc, be_enc, enc_f, encb);
    // ws2 = enc @ [Wg1a | Wg1b | Wi1b] + [0 | bg1 | bi1]   [1536 x 2304]
    gemm48<<<dim3(32, 3), 256, 0, stream>>>(encb, packedW + (size_t)1 * MS,
                                            bias2304, ws2, 2304);
    // ha = intv @ Wi1a                  [768 x 768]
    gemm48<<<dim3(16, 1), 256, 0, stream>>>(intvb, packedW + (size_t)4 * MS,
                                            nullptr, ha, Hp);
    graph_kernel<<<Bp * Vp, 256, 0, stream>>>(ws2, g_g, b_g, Wg2, bg2, graph);
    effects48<<<Bp * Ip, 256, 0, stream>>>(ha, ws2, g_i, b_i,
                                           packedW + (size_t)5 * MS, bi2, effects);
}

// Round 4
// 312.070 us; speedup vs baseline: 1.0762x; 1.0762x over previous
//
#include <hip/hip_runtime.h>
#include <math.h>

#define Bp 32
#define Vp 48
#define Ip 24
#define Hp 768
#define EPS 1e-5f

#define EFFECTS_SIZE (Bp*Ip*Vp*Hp)   // 28,311,552
#define GRAPH_SIZE   (Bp*Vp*Vp)      // 73,728
#define ENC_SIZE     (Bp*Vp*Hp)      // 1,179,648
#define MS           (Hp*Hp)         // packed matrix size in ushorts

typedef __attribute__((ext_vector_type(8))) short short8;
typedef __attribute__((ext_vector_type(4))) float floatx4;
typedef __attribute__((ext_vector_type(4))) unsigned int uintx4;

__device__ __forceinline__ unsigned short f2bf(float f) {
    unsigned int u = __float_as_uint(f);
    u += 0x7fffu + ((u >> 16) & 1u);
    return (unsigned short)(u >> 16);
}
__device__ __forceinline__ unsigned int f2bf2(float a, float b) {
    return (unsigned int)f2bf(a) | ((unsigned int)f2bf(b) << 16);
}

// ---------------------------------------------------------------------------
// Pack 6 H x H weight blocks into MFMA B-operand layout (bf16).
// packed[m][((T*24+kb)*64+lane)*8 + j] = W[kb*32+(lane>>4)*8+j][T*16+(lane&15)]
// slots: 0=W_enc 1=Wg1a 2=Wg1b 3=Wi1b 4=Wi1a 5=Wi2
// ---------------------------------------------------------------------------
__global__ __launch_bounds__(256) void pack_weights(
    const float* __restrict__ W_enc, const float* __restrict__ Wg1,
    const float* __restrict__ Wi1, const float* __restrict__ Wi2,
    unsigned short* __restrict__ packed)
{
    const int bid = blockIdx.x;          // 0..1727
    const int m = bid / 288;
    const int rem = bid - m * 288;
    const int T = rem / 6;
    const int u = rem - T * 6;
    const float* src;
    switch (m) {
        case 0: src = W_enc; break;
        case 1: src = Wg1; break;
        case 2: src = Wg1 + Hp * Hp; break;
        case 3: src = Wi1 + Hp * Hp; break;
        case 4: src = Wi1; break;
        default: src = Wi2; break;
    }
    unsigned short* dst = packed + (size_t)m * MS;
    const int lane = threadIdx.x & 63;
    const int kq = threadIdx.x >> 6;     // 0..3
    const int col = T * 16 + (lane & 15);
    const int krow0 = (lane >> 4) * 8;
    const int kb = kq + 4 * u;           // 0..23
    unsigned int w[4];
#pragma unroll
    for (int p2 = 0; p2 < 4; ++p2) {
        float f0 = src[(size_t)(kb * 32 + krow0 + 2 * p2)     * Hp + col];
        float f1 = src[(size_t)(kb * 32 + krow0 + 2 * p2 + 1) * Hp + col];
        w[p2] = f2bf2(f0, f1);
    }
    uintx4 v; v.x = w[0]; v.y = w[1]; v.z = w[2]; v.w = w[3];
    *(uintx4*)(dst + ((size_t)(T * 24 + kb) * 64 + lane) * 8) = v;
}

// ---------------------------------------------------------------------------
// Convert variables+interventions fp32 -> bf16; block 0 also builds bias2304.
// ---------------------------------------------------------------------------
__global__ __launch_bounds__(256) void convert_inputs(
    const float* __restrict__ vars, const float* __restrict__ intv,
    const float* __restrict__ bg1, const float* __restrict__ bi1,
    unsigned short* __restrict__ varb, unsigned short* __restrict__ intvb,
    float* __restrict__ bias2304)
{
    const int p = blockIdx.x * 256 + threadIdx.x;
    const int VPn = ENC_SIZE / 2;
    if (p < VPn) {
        float2 f = ((const float2*)vars)[p];
        ((unsigned int*)varb)[p] = f2bf2(f.x, f.y);
    } else {
        int q = p - VPn;
        float2 f = ((const float2*)intv)[q];
        ((unsigned int*)intvb)[q] = f2bf2(f.x, f.y);
    }
    if (blockIdx.x == 0) {
        for (int t = threadIdx.x; t < 2304; t += 256)
            bias2304[t] = (t < 768) ? 0.0f : (t < 1536 ? bg1[t - 768] : bi1[t - 1536]);
    }
}

// ---------------------------------------------------------------------------
// gemm32: C[M x N] = A_bf16[M x 768] @ Bpacked (+bias).
// Block = 32 rows x 192 cols (grid.x = M/32, grid.y = N/192). 48 KB LDS.
// Wave tile 32x48 (acc[2][3]); B 3-deep reg prefetch (4 buffers); A dbuf.
// Per-block kb rotation + wave->Tg rotation to de-lockstep L2 B reads.
// ---------------------------------------------------------------------------
__global__ __launch_bounds__(256) void gemm32(
    const unsigned short* __restrict__ A, const unsigned short* __restrict__ Bpk,
    const float* __restrict__ bias, float* __restrict__ C, int ldc)
{
    __shared__ unsigned short Asl[2 * 24 * 64 * 8];   // 49,152 B
    const int tid = threadIdx.x, wave = tid >> 6, lane = tid & 63;
    const int m0 = blockIdx.x * 32;

    // stage A into swizzled fragment layout
#pragma unroll
    for (int uu = 0; uu < 12; ++uu) {
        const int s = tid + 256 * uu;                 // 0..3071
        const int mt = s / 1536;
        const int r2 = s - mt * 1536;
        const int kb = r2 >> 6;
        const int L  = r2 & 63;
        uintx4 v = *(const uintx4*)(A + (size_t)(m0 + mt * 16 + (L & 15)) * Hp
                                      + kb * 32 + (L >> 4) * 8);
        *(uintx4*)(&Asl[((mt * 24 + kb) * 64 + (L ^ (kb & 7))) * 8]) = v;
    }
    __syncthreads();

    const int mrow = lane & 15, kq = lane >> 4;
    const int rot = ((blockIdx.x * 5 + blockIdx.y) & 7) * 3;
    const int wavep = (wave + blockIdx.x) & 3;
    const int Tg0 = blockIdx.y * 12 + wavep * 3;
    const unsigned short* Bbase = Bpk + (size_t)Tg0 * 12288 + lane * 8;

    const floatx4 z = {0.f, 0.f, 0.f, 0.f};
    floatx4 acc[2][3];
#pragma unroll
    for (int mt = 0; mt < 2; ++mt)
#pragma unroll
        for (int nt = 0; nt < 3; ++nt) acc[mt][nt] = z;

    short8 bbuf[4][3], abuf[2][2];
#pragma unroll
    for (int d = 0; d < 3; ++d) {
        int kc = d + rot; if (kc >= 24) kc -= 24;
#pragma unroll
        for (int nt = 0; nt < 3; ++nt)
            bbuf[d][nt] = *(const short8*)(Bbase + (size_t)nt * 12288 + kc * 512);
    }
    {
        int kc = rot;
#pragma unroll
        for (int mt = 0; mt < 2; ++mt)
            abuf[0][mt] = *(const short8*)(&Asl[((mt * 24 + kc) * 64 + (lane ^ (kc & 7))) * 8]);
    }

#pragma unroll
    for (int kb = 0; kb < 24; ++kb) {
        if (kb + 3 < 24) {
            int kc = kb + 3 + rot; if (kc >= 24) kc -= 24;
#pragma unroll
            for (int nt = 0; nt < 3; ++nt)
                bbuf[(kb + 3) & 3][nt] =
                    *(const short8*)(Bbase + (size_t)nt * 12288 + kc * 512);
        }
        if (kb + 1 < 24) {
            int kc = kb + 1 + rot; if (kc >= 24) kc -= 24;
#pragma unroll
            for (int mt = 0; mt < 2; ++mt)
                abuf[(kb + 1) & 1][mt] = *(const short8*)(
                    &Asl[((mt * 24 + kc) * 64 + (lane ^ (kc & 7))) * 8]);
        }
#pragma unroll
        for (int mt = 0; mt < 2; ++mt)
#pragma unroll
            for (int nt = 0; nt < 3; ++nt)
                acc[mt][nt] = __builtin_amdgcn_mfma_f32_16x16x32_bf16(
                    abuf[kb & 1][mt], bbuf[kb & 3][nt], acc[mt][nt], 0, 0, 0);
    }

#pragma unroll
    for (int nt = 0; nt < 3; ++nt) {
        const int colg = (Tg0 + nt) * 16 + mrow;
        const float bv = bias ? bias[colg] : 0.0f;
#pragma unroll
        for (int mt = 0; mt < 2; ++mt)
#pragma unroll
            for (int r = 0; r < 4; ++r)
                C[(size_t)(m0 + mt * 16 + kq * 4 + r) * ldc + colg] = acc[mt][nt][r] + bv;
    }
}

// ---------------------------------------------------------------------------
// LN+ReLU -> enc fp32 (output) and enc bf16 (next GEMM A)
// ---------------------------------------------------------------------------
__global__ __launch_bounds__(256) void ln_relu(
    const float* __restrict__ pre, const float* __restrict__ g,
    const float* __restrict__ be, float* __restrict__ encf,
    unsigned short* __restrict__ encb)
{
    const int wave = threadIdx.x >> 6, lane = threadIdx.x & 63;
    const int row = blockIdx.x * 4 + wave;
    const float2* rp = (const float2*)(pre + (size_t)row * Hp);
    float2 x[6]; float s = 0.f, q = 0.f;
#pragma unroll
    for (int c = 0; c < 6; ++c) {
        x[c] = rp[lane + 64 * c];
        s += x[c].x + x[c].y;
        q += x[c].x * x[c].x + x[c].y * x[c].y;
    }
#pragma unroll
    for (int m = 1; m < 64; m <<= 1) { s += __shfl_xor(s, m, 64); q += __shfl_xor(q, m, 64); }
    const float mu = s * (1.0f / Hp);
    const float var = q * (1.0f / Hp) - mu * mu;
    const float rs = rsqrtf(var + EPS);
    float2* of = (float2*)(encf + (size_t)row * Hp);
    unsigned int* ob = (unsigned int*)(encb + (size_t)row * Hp);
#pragma unroll
    for (int c = 0; c < 6; ++c) {
        const float2 g2 = ((const float2*)g)[lane + 64 * c];
        const float2 b2 = ((const float2*)be)[lane + 64 * c];
        float y0 = fmaxf((x[c].x - mu) * rs * g2.x + b2.x, 0.f);
        float y1 = fmaxf((x[c].y - mu) * rs * g2.y + b2.y, 0.f);
        of[lane + 64 * c] = make_float2(y0, y1);
        ob[lane + 64 * c] = f2bf2(y0, y1);
    }
}

// ---------------------------------------------------------------------------
// Causal graph: block = (b,i); each wave handles 12 j's.
// ---------------------------------------------------------------------------
__global__ __launch_bounds__(256) void graph_kernel(
    const float* __restrict__ ws2, const float* __restrict__ gg_,
    const float* __restrict__ bb_, const float* __restrict__ Wg2,
    const float* __restrict__ bg2, float* __restrict__ out)
{
    const int wave = threadIdx.x >> 6, lane = threadIdx.x & 63;
    const int p = blockIdx.x;
    const int b = p / Vp, i = p - b * Vp;
    const float* hi_row = ws2 + (size_t)p * 2304;
    float ri[12], gg[12], bb[12], w2[12];
#pragma unroll
    for (int c = 0; c < 12; ++c) {
        const int k = lane + 64 * c;
        ri[c] = hi_row[k]; gg[c] = gg_[k]; bb[c] = bb_[k]; w2[c] = Wg2[k];
    }
    const float bg2v = bg2[0];
    const int j0 = wave * 12;
    for (int jj = 0; jj < 12; ++jj) {
        const int j = j0 + jj;
        const float* hj_row = ws2 + (size_t)(b * Vp + j) * 2304 + 768;
        float x[12], s = 0.f, q = 0.f;
#pragma unroll
        for (int c = 0; c < 12; ++c) {
            x[c] = ri[c] + hj_row[lane + 64 * c];
            s += x[c]; q += x[c] * x[c];
        }
#pragma unroll
        for (int m = 1; m < 64; m <<= 1) { s += __shfl_xor(s, m, 64); q += __shfl_xor(q, m, 64); }
        const float mu = s * (1.0f / Hp);
        const float var = q * (1.0f / Hp) - mu * mu;
        const float rs = rsqrtf(var + EPS);
        float pd = 0.f;
#pragma unroll
        for (int c = 0; c < 12; ++c) {
            float y = fmaxf((x[c] - mu) * rs * gg[c] + bb[c], 0.f);
            pd = fmaf(y, w2[c], pd);
        }
#pragma unroll
        for (int m = 1; m < 64; m <<= 1) pd += __shfl_xor(pd, m, 64);
        if (lane == 0) {
            float sc = (i == j) ? 0.0f : 1.0f / (1.0f + expf(-(pd + bg2v)));
            out[(size_t)p * Vp + j] = sc;
        }
    }
}

// ---------------------------------------------------------------------------
// effects48: block = one (b,i) pair x all 48 j's.
// Phase 1: LN+ReLU -> bf16 swizzled-fragment LDS.
// Phase 2: pipelined MFMA vs packed Wi2, with per-block kb/Tg rotation
//          (de-lockstep L2 reads) and 3-deep B prefetch.
// ---------------------------------------------------------------------------
__global__ __launch_bounds__(256) void effects48(
    const float* __restrict__ ha, const float* __restrict__ ws2,
    const float* __restrict__ g_i, const float* __restrict__ b_i,
    const unsigned short* __restrict__ Bpk, const float* __restrict__ bi2,
    float* __restrict__ out)
{
    __shared__ unsigned short Asl[3 * 24 * 64 * 8];   // 73,728 B
    const int tid = threadIdx.x, wave = tid >> 6, lane = tid & 63;
    const int bi = blockIdx.x;           // 0..767 = b*Ip + i
    const int b = bi / Ip;
    const int half = lane >> 5, hl = lane & 31;

    const floatx4* hap = (const floatx4*)(ha + (size_t)bi * Hp);
    const floatx4* gp = (const floatx4*)g_i;
    const floatx4* bp = (const floatx4*)b_i;
    floatx4 hav[6], gv[6], bv[6];
#pragma unroll
    for (int t = 0; t < 3; ++t) {
        hav[2*t]   = hap[2*hl + 64*t];     hav[2*t+1] = hap[2*hl + 1 + 64*t];
        gv[2*t]    = gp[2*hl + 64*t];      gv[2*t+1]  = gp[2*hl + 1 + 64*t];
        bv[2*t]    = bp[2*hl + 64*t];      bv[2*t+1]  = bp[2*hl + 1 + 64*t];
    }

#pragma unroll
    for (int p = 0; p < 6; ++p) {
        const int u = wave * 12 + 2 * p + half;       // local row = j, 0..47
        const floatx4* hbp = (const floatx4*)(ws2 + (size_t)(b * Vp + u) * 2304 + 1536);
        floatx4 x[6]; float s = 0.f, q = 0.f;
#pragma unroll
        for (int t = 0; t < 3; ++t) {
            x[2*t]   = hav[2*t]   + hbp[2*hl + 64*t];
            x[2*t+1] = hav[2*t+1] + hbp[2*hl + 1 + 64*t];
        }
#pragma unroll
        for (int c = 0; c < 6; ++c) {
            s += x[c].x + x[c].y + x[c].z + x[c].w;
            q += x[c].x*x[c].x + x[c].y*x[c].y + x[c].z*x[c].z + x[c].w*x[c].w;
        }
#pragma unroll
        for (int m = 1; m < 32; m <<= 1) { s += __shfl_xor(s, m, 64); q += __shfl_xor(q, m, 64); }
        const float mu = s * (1.0f / Hp);
        const float var = q * (1.0f / Hp) - mu * mu;
        const float rs = rsqrtf(var + EPS);
        const int mt = u >> 4, mrow = u & 15;
#pragma unroll
        for (int t = 0; t < 3; ++t) {
            float y0 = fmaxf((x[2*t].x   - mu) * rs * gv[2*t].x   + bv[2*t].x,   0.f);
            float y1 = fmaxf((x[2*t].y   - mu) * rs * gv[2*t].y   + bv[2*t].y,   0.f);
            float y2 = fmaxf((x[2*t].z   - mu) * rs * gv[2*t].z   + bv[2*t].z,   0.f);
            float y3 = fmaxf((x[2*t].w   - mu) * rs * gv[2*t].w   + bv[2*t].w,   0.f);
            float y4 = fmaxf((x[2*t+1].x - mu) * rs * gv[2*t+1].x + bv[2*t+1].x, 0.f);
            float y5 = fmaxf((x[2*t+1].y - mu) * rs * gv[2*t+1].y + bv[2*t+1].y, 0.f);
            float y6 = fmaxf((x[2*t+1].z - mu) * rs * gv[2*t+1].z + bv[2*t+1].z, 0.f);
            float y7 = fmaxf((x[2*t+1].w - mu) * rs * gv[2*t+1].w + bv[2*t+1].w, 0.f);
            const int cpk = hl + 32 * t;              // chunk 0..95
            const int kb = cpk >> 2, kq2 = cpk & 3;
            const int phys = (mt * 24 + kb) * 64 + ((kq2 * 16 + mrow) ^ (kb & 7));
            uintx4 v;
            v.x = f2bf2(y0, y1); v.y = f2bf2(y2, y3);
            v.z = f2bf2(y4, y5); v.w = f2bf2(y6, y7);
            *(uintx4*)(&Asl[phys * 8]) = v;
        }
    }
    __syncthreads();

    // ---- Phase 2 ----
    const int mrow = lane & 15, kq = lane >> 4;
    const int rot = (bi & 7) * 3;
    const int wavep = (wave + bi) & 3;
    const floatx4 z = {0.f, 0.f, 0.f, 0.f};
#pragma unroll
    for (int G = 0; G < 2; ++G) {
        const int Tg0 = wavep * 12 + G * 6;
        const unsigned short* Bbase = Bpk + (size_t)Tg0 * 12288 + lane * 8;
        floatx4 acc[3][6];
#pragma unroll
        for (int mt = 0; mt < 3; ++mt)
#pragma unroll
            for (int nt = 0; nt < 6; ++nt) acc[mt][nt] = z;

        short8 bbuf[4][6], abuf[2][3];
#pragma unroll
        for (int d = 0; d < 3; ++d) {
            int kc = d + rot; if (kc >= 24) kc -= 24;
#pragma unroll
            for (int nt = 0; nt < 6; ++nt)
                bbuf[d][nt] = *(const short8*)(Bbase + (size_t)nt * 12288 + kc * 512);
        }
        {
            int kc = rot;
#pragma unroll
            for (int mt = 0; mt < 3; ++mt)
                abuf[0][mt] = *(const short8*)(&Asl[((mt * 24 + kc) * 64 + (lane ^ (kc & 7))) * 8]);
        }

#pragma unroll
        for (int kb = 0; kb < 24; ++kb) {
            if (kb + 3 < 24) {
                int kc = kb + 3 + rot; if (kc >= 24) kc -= 24;
#pragma unroll
                for (int nt = 0; nt < 6; ++nt)
                    bbuf[(kb + 3) & 3][nt] =
                        *(const short8*)(Bbase + (size_t)nt * 12288 + kc * 512);
            }
            if (kb + 1 < 24) {
                int kc = kb + 1 + rot; if (kc >= 24) kc -= 24;
#pragma unroll
                for (int mt = 0; mt < 3; ++mt)
                    abuf[(kb + 1) & 1][mt] = *(const short8*)(
                        &Asl[((mt * 24 + kc) * 64 + (lane ^ (kc & 7))) * 8]);
            }
#pragma unroll
            for (int mt = 0; mt < 3; ++mt)
#pragma unroll
                for (int nt = 0; nt < 6; ++nt)
                    acc[mt][nt] = __builtin_amdgcn_mfma_f32_16x16x32_bf16(
                        abuf[kb & 1][mt], bbuf[kb & 3][nt], acc[mt][nt], 0, 0, 0);
        }

#pragma unroll
        for (int nt = 0; nt < 6; ++nt) {
            const int colg = (Tg0 + nt) * 16 + mrow;
            const float biasv = bi2[colg];
#pragma unroll
            for (int mt = 0; mt < 3; ++mt) {
#pragma unroll
                for (int r = 0; r < 4; ++r) {
                    out[(size_t)(bi * 48 + mt * 16 + kq * 4 + r) * Hp + colg] =
                        acc[mt][nt][r] + biasv;
                }
            }
        }
    }
}

// ---------------------------------------------------------------------------
extern "C" void kernel_launch(void* const* d_in, const int* in_sizes, int n_in,
                              void* d_out, int out_size, void* d_ws, size_t ws_size,
                              hipStream_t stream) {
    const float* variables     = (const float*)d_in[0];
    const float* interventions = (const float*)d_in[1];
    const float* W_enc  = (const float*)d_in[2];
    const float* b_enc  = (const float*)d_in[3];
    const float* g_enc  = (const float*)d_in[4];
    const float* be_enc = (const float*)d_in[5];
    const float* Wg1 = (const float*)d_in[6];
    const float* bg1 = (const float*)d_in[7];
    const float* g_g = (const float*)d_in[8];
    const float* b_g = (const float*)d_in[9];
    const float* Wg2 = (const float*)d_in[10];
    const float* bg2 = (const float*)d_in[11];
    const float* Wi1 = (const float*)d_in[12];
    const float* bi1 = (const float*)d_in[13];
    const float* g_i = (const float*)d_in[14];
    const float* b_i = (const float*)d_in[15];
    const float* Wi2 = (const float*)d_in[16];
    const float* bi2 = (const float*)d_in[17];

    float* out = (float*)d_out;
    float* effects = out;
    float* graph = out + EFFECTS_SIZE;
    float* enc_f = out + EFFECTS_SIZE + GRAPH_SIZE;

    char* wsb = (char*)d_ws;
    unsigned short* packedW = (unsigned short*)wsb;                   // 7,077,888 B
    float* ws2  = (float*)(wsb + 7077888);                            // [1536][2304] fp32
    float* pre1 = ws2;                                                // alias (consumed first)
    float* ha   = (float*)(wsb + 7077888 + 14155776);                 // [768][768] fp32
    unsigned short* varb  = (unsigned short*)(wsb + 23592960);
    unsigned short* intvb = (unsigned short*)(wsb + 25952256);
    unsigned short* encb  = (unsigned short*)(wsb + 27131904);
    float* bias2304 = (float*)(wsb + 29491200);

    pack_weights<<<1728, 256, 0, stream>>>(W_enc, Wg1, Wi1, Wi2, packedW);
    convert_inputs<<<3456, 256, 0, stream>>>(variables, interventions, bg1, bi1,
                                             varb, intvb, bias2304);
    // pre1 = var @ W_enc + b_enc        [1536 x 768]
    gemm32<<<dim3(48, 4), 256, 0, stream>>>(varb, packedW, b_enc, pre1, Hp);
    // enc (fp32 to d_out, bf16 to ws)
    ln_relu<<<384, 256, 0, stream>>>(pre1, g_enc, be_enc, enc_f, encb);
    // ws2 = enc @ [Wg1a | Wg1b | Wi1b] + [0 | bg1 | bi1]   [1536 x 2304]
    gemm32<<<dim3(48, 12), 256, 0, stream>>>(encb, packedW + (size_t)1 * MS,
                                             bias2304, ws2, 2304);
    // ha = intv @ Wi1a                  [768 x 768]
    gemm32<<<dim3(24, 4), 256, 0, stream>>>(intvb, packedW + (size_t)4 * MS,
                                            nullptr, ha, Hp);
    graph_kernel<<<Bp * Vp, 256, 0, stream>>>(ws2, g_g, b_g, Wg2, bg2, graph);
    effects48<<<Bp * Ip, 256, 0, stream>>>(ha, ws2, g_i, b_i,
                                           packedW + (size_t)5 * MS, bi2, effects);
}